// Round 1
// baseline (3985.793 us; speedup 1.0000x reference)
//
#include <hip/hip_runtime.h>

#define NN 100000
#define NE 600000
#define NG 512
#define D 128
#define NL 3
#define EPS 1e-5f

// ---------------------------------------------------------------------------
// Edge scatter-add: G[dst] += hin[src]  (G pre-initialized to hin / h)
// thread t: edge e = t/32, feature-quad f4 = t%32 (float4 per thread)
// ---------------------------------------------------------------------------
__global__ __launch_bounds__(256) void k_scatter(const float4* __restrict__ hin,
                                                 const int* __restrict__ ei,
                                                 float* __restrict__ g) {
    long t = (long)blockIdx.x * 256 + threadIdx.x;
    int e = (int)(t >> 5);
    if (e >= NE) return;
    int f4 = (int)(t & 31);
    int s = ei[e];
    int d = ei[NE + e];
    float4 v = hin[(long)s * 32 + f4];
    float* dst = g + (long)d * D + f4 * 4;
    atomicAdd(dst + 0, v.x);
    atomicAdd(dst + 1, v.y);
    atomicAdd(dst + 2, v.z);
    atomicAdd(dst + 3, v.w);
}

// ---------------------------------------------------------------------------
// fp32 GEMM: C[M x 128] = A[M x 128] @ W[128 x 128] + bias[128]
// BM=64 rows/block, 256 threads, micro-tile 4x8. W fully in LDS (quad-swizzled
// to break the 32B-stride 4-way bank conflict), A staged transposed per BK=32
// chunk so fragment reads are conflict-free ds_read_b128.
// LDS = 64KB (Ws) + 8.5KB (AsT) -> 2 blocks/CU.
// ---------------------------------------------------------------------------
#define BM 64
#define BK 32
#define AST 68  // padded row stride (floats) for AsT[k][row]

__global__ __launch_bounds__(256) void k_gemm(const float* __restrict__ A,
                                              const float* __restrict__ W,
                                              const float* __restrict__ bias,
                                              float* __restrict__ C) {
    __shared__ float Ws[128 * 128];
    __shared__ float As[BK * AST];
    const int tid = threadIdx.x;
    const int ty = tid >> 4;   // 0..15 -> rows ty*4..+3
    const int tx = tid & 15;   // 0..15 -> cols tx*8..+7
    const long base = (long)blockIdx.x * BM;

    // Load W -> LDS with quad permutation p(q) = (q&1)*16 + q>>1
    #pragma unroll
    for (int j = 0; j < 16; ++j) {
        int e = tid * 4 + j * 1024;
        int k = e >> 7, col = e & 127;
        int q = col >> 2;
        int p = ((q & 1) << 4) + (q >> 1);
        float4 v = *(const float4*)(W + (long)k * 128 + col);
        *(float4*)(&Ws[k * 128 + p * 4]) = v;
    }

    float acc[4][8];
    #pragma unroll
    for (int i = 0; i < 4; ++i)
        #pragma unroll
        for (int c = 0; c < 8; ++c) acc[i][c] = 0.f;

    for (int kc = 0; kc < 128; kc += BK) {
        // stage A chunk transposed: AsT[k][row]
        #pragma unroll
        for (int j = 0; j < 2; ++j) {
            int e = tid * 4 + j * 1024;
            int row = e >> 5, col = e & 31;
            long gr = base + row;
            float4 v = make_float4(0.f, 0.f, 0.f, 0.f);
            if (gr < NN) v = *(const float4*)(A + gr * D + kc + col);
            As[(col + 0) * AST + row] = v.x;
            As[(col + 1) * AST + row] = v.y;
            As[(col + 2) * AST + row] = v.z;
            As[(col + 3) * AST + row] = v.w;
        }
        __syncthreads();
        #pragma unroll
        for (int k = 0; k < BK; ++k) {
            float4 a4 = *(const float4*)(&As[k * AST + ty * 4]);
            // swizzled reads: physical quad c4*16+tx holds logical cols tx*8+4*c4
            float4 w0 = *(const float4*)(&Ws[(kc + k) * 128 + tx * 4]);
            float4 w1 = *(const float4*)(&Ws[(kc + k) * 128 + 64 + tx * 4]);
            float av[4] = {a4.x, a4.y, a4.z, a4.w};
            float wv[8] = {w0.x, w0.y, w0.z, w0.w, w1.x, w1.y, w1.z, w1.w};
            #pragma unroll
            for (int i = 0; i < 4; ++i)
                #pragma unroll
                for (int c = 0; c < 8; ++c) acc[i][c] = fmaf(av[i], wv[c], acc[i][c]);
        }
        __syncthreads();
    }

    float b[8];
    #pragma unroll
    for (int c = 0; c < 8; ++c) b[c] = bias[tx * 8 + c];
    #pragma unroll
    for (int i = 0; i < 4; ++i) {
        long gr = base + ty * 4 + i;
        if (gr < NN) {
            float4 s0 = make_float4(acc[i][0] + b[0], acc[i][1] + b[1],
                                    acc[i][2] + b[2], acc[i][3] + b[3]);
            float4 s1 = make_float4(acc[i][4] + b[4], acc[i][5] + b[5],
                                    acc[i][6] + b[6], acc[i][7] + b[7]);
            *(float4*)(C + gr * D + tx * 8) = s0;
            *(float4*)(C + gr * D + tx * 8 + 4) = s1;
        }
    }
}

// ---------------------------------------------------------------------------
// Column stats: sum/sumsq over rows (atomic partials)
// ---------------------------------------------------------------------------
__global__ __launch_bounds__(256) void k_stats(const float* __restrict__ Y,
                                               float* __restrict__ sum,
                                               float* __restrict__ sq) {
    int f = threadIdx.x & 127;
    int half = threadIdx.x >> 7;
    float s = 0.f, q = 0.f;
    for (long r = (long)blockIdx.x * 2 + half; r < NN; r += (long)gridDim.x * 2) {
        float v = Y[r * D + f];
        s += v;
        q += v * v;
    }
    atomicAdd(sum + f, s);
    atomicAdd(sq + f, q);
}

// BN1 constants: a1 = g1*rsqrt(v+eps), c1 = bt1 - m*a1 ; biasF init = b2
__global__ void k_fin1(const float* __restrict__ sum, const float* __restrict__ sq,
                       const float* __restrict__ g1, const float* __restrict__ bt1,
                       const float* __restrict__ b2, float* __restrict__ a1,
                       float* __restrict__ c1, float* __restrict__ biasF) {
    int f = threadIdx.x;
    float m = sum[f] * (1.f / NN);
    float v = sq[f] * (1.f / NN) - m * m;
    float a = g1[f] * rsqrtf(v + EPS);
    a1[f] = a;
    c1[f] = bt1[f] - m * a;
    biasF[f] = b2[f];
}

// Fold BN1 into GEMM2 operands: W2s[k][j] = a1[k]*W2[k][j]; biasF[j] += c1[k]*W2[k][j]
__global__ __launch_bounds__(128) void k_fold(const float* __restrict__ W2,
                                              const float* __restrict__ a1,
                                              const float* __restrict__ c1,
                                              float* __restrict__ W2s,
                                              float* __restrict__ biasF) {
    int k = blockIdx.x, j = threadIdx.x;
    float w = W2[(long)k * 128 + j];
    W2s[(long)k * 128 + j] = a1[k] * w;
    atomicAdd(biasF + j, c1[k] * w);
}

// BN2 + outer BN collapse: A = rs2*g2*rso*go, B = bo - m2*A
// (mean(BN2out)=bt2 cancels; var(BN2out)=(rs2*g2)^2*v2 analytically)
__global__ void k_fin2(const float* __restrict__ sum, const float* __restrict__ sq,
                       const float* __restrict__ g2, const float* __restrict__ go,
                       const float* __restrict__ bo, float* __restrict__ affA,
                       float* __restrict__ affB) {
    int f = threadIdx.x;
    float m = sum[f] * (1.f / NN);
    float v = sq[f] * (1.f / NN) - m * m;
    float t = g2[f] * rsqrtf(v + EPS);   // rs2*g2
    float vo = t * t * v;                // var of BN2 output
    float Aa = t * rsqrtf(vo + EPS) * go[f];
    affA[f] = Aa;
    affB[f] = bo[f] - m * Aa;
}

// h_next = relu(y2*A + B), written to o1 (and o2 for next layer's agg init)
__global__ __launch_bounds__(256) void k_affine(const float4* __restrict__ Y,
                                                const float* __restrict__ affA,
                                                const float* __restrict__ affB,
                                                float4* __restrict__ o1,
                                                float4* __restrict__ o2) {
    const long n4 = (long)NN * 32;
    for (long i = (long)blockIdx.x * 256 + threadIdx.x; i < n4;
         i += (long)gridDim.x * 256) {
        int c4 = (int)(i & 31) * 4;
        float4 v = Y[i];
        float4 A = *(const float4*)(affA + c4);
        float4 B = *(const float4*)(affB + c4);
        float4 r;
        r.x = fmaxf(fmaf(v.x, A.x, B.x), 0.f);
        r.y = fmaxf(fmaf(v.y, A.y, B.y), 0.f);
        r.z = fmaxf(fmaf(v.z, A.z, B.z), 0.f);
        r.w = fmaxf(fmaf(v.w, A.w, B.w), 0.f);
        o1[i] = r;
        if (o2) o2[i] = r;
    }
}

__device__ __forceinline__ int lower_bound_i(const int* __restrict__ a, int n, int v) {
    int lo = 0, hi = n;
    while (lo < hi) {
        int m = (lo + hi) >> 1;
        if (a[m] < v) lo = m + 1; else hi = m;
    }
    return lo;
}

// Per-graph mean pool (batch is sorted) + fc(128->2)
__global__ __launch_bounds__(128) void k_pool(const float* __restrict__ h,
                                              const int* __restrict__ batch,
                                              const float* __restrict__ fcW,
                                              const float* __restrict__ fcb,
                                              float* __restrict__ ge,
                                              float* __restrict__ out) {
    __shared__ float r0[128], r1[128];
    int g = blockIdx.x, j = threadIdx.x;
    int lo = lower_bound_i(batch, NN, g);
    int hi = lower_bound_i(batch, NN, g + 1);
    float s = 0.f;
    for (int r = lo; r < hi; ++r) s += h[(long)r * D + j];
    int cnt = hi - lo;
    float mean = s / (float)(cnt > 0 ? cnt : 1);
    ge[(long)g * D + j] = mean;
    r0[j] = mean * fcW[j * 2 + 0];
    r1[j] = mean * fcW[j * 2 + 1];
    __syncthreads();
    for (int st = 64; st > 0; st >>= 1) {
        if (j < st) { r0[j] += r0[j + st]; r1[j] += r1[j + st]; }
        __syncthreads();
    }
    if (j == 0) {
        out[g * 2 + 0] = r0[0] + fcb[0];
        out[g * 2 + 1] = r1[0] + fcb[1];
    }
}

// ---------------------------------------------------------------------------
extern "C" void kernel_launch(void* const* d_in, const int* in_sizes, int n_in,
                              void* d_out, int out_size, void* d_ws, size_t ws_size,
                              hipStream_t stream) {
    const float* x   = (const float*)d_in[0];
    const int*   ei  = (const int*)d_in[1];
    const int*   bat = (const int*)d_in[2];
    const float* W1  = (const float*)d_in[3];
    const float* b1  = (const float*)d_in[4];
    const float* g1  = (const float*)d_in[5];
    const float* bt1 = (const float*)d_in[6];
    const float* W2  = (const float*)d_in[7];
    const float* b2  = (const float*)d_in[8];
    const float* g2  = (const float*)d_in[9];
    // d_in[10] = bt2: cancels analytically (mean of BN2 output)
    const float* go  = (const float*)d_in[11];
    const float* bo  = (const float*)d_in[12];
    const float* fcW = (const float*)d_in[13];
    const float* fcb = (const float*)d_in[14];

    const long ND = (long)NN * D;
    float* H = (float*)d_ws;      // h (next-layer input)
    float* G = H + ND;            // aggregate / y2
    float* S = G + ND;            // small constants region
    float* sum   = S;             // 128
    float* sq    = S + 128;       // 128
    float* a1    = S + 256;
    float* c1    = S + 384;
    float* biasF = S + 512;
    float* affA  = S + 640;
    float* affB  = S + 768;
    float* W2s   = S + 1024;      // 128*128

    float* nodeEmb = (float*)d_out;        // also reused as GEMM1 scratch Y
    float* ge   = nodeEmb + ND;
    float* out2 = ge + (long)NG * D;
    float* Y = nodeEmb;

    const int gemmGrid = (NN + BM - 1) / BM;   // 1563
    const int scatGrid = (int)(((long)NE * 32 + 255) / 256);  // 75000

    for (int l = 0; l < NL; ++l) {
        const float* hin = (l == 0) ? x : H;
        if (l == 0)
            hipMemcpyAsync(G, x, sizeof(float) * ND, hipMemcpyDeviceToDevice, stream);
        // G already = h for l>0 (written by k_affine)
        k_scatter<<<scatGrid, 256, 0, stream>>>((const float4*)hin, ei, G);

        hipMemsetAsync(sum, 0, 256 * sizeof(float), stream);
        k_gemm<<<gemmGrid, 256, 0, stream>>>(G, W1 + (long)l * D * D, b1 + l * D, Y);
        k_stats<<<512, 256, 0, stream>>>(Y, sum, sq);
        k_fin1<<<1, 128, 0, stream>>>(sum, sq, g1 + l * D, bt1 + l * D, b2 + l * D,
                                      a1, c1, biasF);
        k_fold<<<128, 128, 0, stream>>>(W2 + (long)l * D * D, a1, c1, W2s, biasF);

        hipMemsetAsync(sum, 0, 256 * sizeof(float), stream);
        k_gemm<<<gemmGrid, 256, 0, stream>>>(Y, W2s, biasF, G);
        k_stats<<<512, 256, 0, stream>>>(G, sum, sq);
        k_fin2<<<1, 128, 0, stream>>>(sum, sq, g2 + l * D, go + l * D, bo + l * D,
                                      affA, affB);

        float*  o1 = (l == NL - 1) ? nodeEmb : H;
        float4* o2 = (l == NL - 1) ? nullptr : (float4*)G;  // in-place ok (same elem)
        k_affine<<<4096, 256, 0, stream>>>((const float4*)G, affA, affB,
                                           (float4*)o1, o2);
    }

    k_pool<<<NG, 128, 0, stream>>>(nodeEmb, bat, fcW, fcb, ge, out2);
}

// Round 2
// 1133.597 us; speedup vs baseline: 3.5161x; 3.5161x over previous
//
#include <hip/hip_runtime.h>

#define NN 100000
#define NE 600000
#define NG 512
#define D 128
#define NL 3
#define EPS 1e-5f

// ---------------------------------------------------------------------------
// CSR build: histogram -> exclusive scan -> fill (sorted-by-dst source list)
// ---------------------------------------------------------------------------
__global__ __launch_bounds__(256) void k_hist(const int* __restrict__ ei,
                                              int* __restrict__ deg) {
    int e = blockIdx.x * 256 + threadIdx.x;
    if (e < NE) atomicAdd(&deg[ei[NE + e]], 1);
}

__global__ __launch_bounds__(256) void k_scan1(const int* __restrict__ deg,
                                               int* __restrict__ excl,
                                               int* __restrict__ bsum) {
    __shared__ int s[256];
    int i = blockIdx.x * 256 + threadIdx.x;
    int v = (i < NN) ? deg[i] : 0;
    s[threadIdx.x] = v;
    __syncthreads();
    #pragma unroll
    for (int st = 1; st < 256; st <<= 1) {
        int t = (threadIdx.x >= st) ? s[threadIdx.x - st] : 0;
        __syncthreads();
        s[threadIdx.x] += t;
        __syncthreads();
    }
    if (i < NN) excl[i] = s[threadIdx.x] - v;
    if (threadIdx.x == 255) bsum[blockIdx.x] = s[255];
}

__global__ __launch_bounds__(512) void k_scan2(int* __restrict__ bsum, int nb) {
    __shared__ int s[512];
    int v = (threadIdx.x < nb) ? bsum[threadIdx.x] : 0;
    s[threadIdx.x] = v;
    __syncthreads();
    #pragma unroll
    for (int st = 1; st < 512; st <<= 1) {
        int t = (threadIdx.x >= st) ? s[threadIdx.x - st] : 0;
        __syncthreads();
        s[threadIdx.x] += t;
        __syncthreads();
    }
    if (threadIdx.x < nb) bsum[threadIdx.x] = s[threadIdx.x] - v;  // exclusive
}

__global__ __launch_bounds__(256) void k_scan3(const int* __restrict__ excl,
                                               const int* __restrict__ bsum,
                                               int* __restrict__ off,
                                               int* __restrict__ cur) {
    int i = blockIdx.x * 256 + threadIdx.x;
    if (i < NN) {
        int o = excl[i] + bsum[blockIdx.x];
        off[i] = o;
        cur[i] = o;
    }
    if (i == 0) off[NN] = NE;
}

__global__ __launch_bounds__(256) void k_fill(const int* __restrict__ ei,
                                              int* __restrict__ cur,
                                              int* __restrict__ srcs) {
    int e = blockIdx.x * 256 + threadIdx.x;
    if (e < NE) {
        int d = ei[NE + e];
        int p = atomicAdd(&cur[d], 1);
        srcs[p] = ei[e];
    }
}

// ---------------------------------------------------------------------------
// Gather aggregation: G[n] = hin[n] + sum_{s in N_in(n)} hin[s]
// 32 lanes per node (float4/lane); each edge = one coalesced 512B row read.
// ---------------------------------------------------------------------------
__global__ __launch_bounds__(256) void k_gather(const float4* __restrict__ hin,
                                                const int* __restrict__ off,
                                                const int* __restrict__ srcs,
                                                float4* __restrict__ g) {
    int t = blockIdx.x * 256 + threadIdx.x;
    int n = t >> 5;
    if (n >= NN) return;
    int f4 = t & 31;
    int lo = off[n], hi = off[n + 1];
    float4 acc = hin[(long)n * 32 + f4];
    for (int e = lo; e < hi; ++e) {
        int s = srcs[e];
        float4 v = hin[(long)s * 32 + f4];
        acc.x += v.x; acc.y += v.y; acc.z += v.z; acc.w += v.w;
    }
    g[(long)n * 32 + f4] = acc;
}

// ---------------------------------------------------------------------------
// fp32 GEMM: C[M x 128] = A[M x 128] @ W[128 x 128] + bias[128]
// BM=64 rows/block, 256 threads, micro-tile 4x8. W fully in LDS (quad-swizzled),
// A staged transposed per BK=32 chunk for conflict-free b128 fragment reads.
// ---------------------------------------------------------------------------
#define BM 64
#define BK 32
#define AST 68

__global__ __launch_bounds__(256) void k_gemm(const float* __restrict__ A,
                                              const float* __restrict__ W,
                                              const float* __restrict__ bias,
                                              float* __restrict__ C) {
    __shared__ float Ws[128 * 128];
    __shared__ float As[BK * AST];
    const int tid = threadIdx.x;
    const int ty = tid >> 4;
    const int tx = tid & 15;
    const long base = (long)blockIdx.x * BM;

    #pragma unroll
    for (int j = 0; j < 16; ++j) {
        int e = tid * 4 + j * 1024;
        int k = e >> 7, col = e & 127;
        int q = col >> 2;
        int p = ((q & 1) << 4) + (q >> 1);
        float4 v = *(const float4*)(W + (long)k * 128 + col);
        *(float4*)(&Ws[k * 128 + p * 4]) = v;
    }

    float acc[4][8];
    #pragma unroll
    for (int i = 0; i < 4; ++i)
        #pragma unroll
        for (int c = 0; c < 8; ++c) acc[i][c] = 0.f;

    for (int kc = 0; kc < 128; kc += BK) {
        #pragma unroll
        for (int j = 0; j < 2; ++j) {
            int e = tid * 4 + j * 1024;
            int row = e >> 5, col = e & 31;
            long gr = base + row;
            float4 v = make_float4(0.f, 0.f, 0.f, 0.f);
            if (gr < NN) v = *(const float4*)(A + gr * D + kc + col);
            As[(col + 0) * AST + row] = v.x;
            As[(col + 1) * AST + row] = v.y;
            As[(col + 2) * AST + row] = v.z;
            As[(col + 3) * AST + row] = v.w;
        }
        __syncthreads();
        #pragma unroll
        for (int k = 0; k < BK; ++k) {
            float4 a4 = *(const float4*)(&As[k * AST + ty * 4]);
            float4 w0 = *(const float4*)(&Ws[(kc + k) * 128 + tx * 4]);
            float4 w1 = *(const float4*)(&Ws[(kc + k) * 128 + 64 + tx * 4]);
            float av[4] = {a4.x, a4.y, a4.z, a4.w};
            float wv[8] = {w0.x, w0.y, w0.z, w0.w, w1.x, w1.y, w1.z, w1.w};
            #pragma unroll
            for (int i = 0; i < 4; ++i)
                #pragma unroll
                for (int c = 0; c < 8; ++c) acc[i][c] = fmaf(av[i], wv[c], acc[i][c]);
        }
        __syncthreads();
    }

    float b[8];
    #pragma unroll
    for (int c = 0; c < 8; ++c) b[c] = bias[tx * 8 + c];
    #pragma unroll
    for (int i = 0; i < 4; ++i) {
        long gr = base + ty * 4 + i;
        if (gr < NN) {
            float4 s0 = make_float4(acc[i][0] + b[0], acc[i][1] + b[1],
                                    acc[i][2] + b[2], acc[i][3] + b[3]);
            float4 s1 = make_float4(acc[i][4] + b[4], acc[i][5] + b[5],
                                    acc[i][6] + b[6], acc[i][7] + b[7]);
            *(float4*)(C + gr * D + tx * 8) = s0;
            *(float4*)(C + gr * D + tx * 8 + 4) = s1;
        }
    }
}

// ---------------------------------------------------------------------------
__global__ __launch_bounds__(256) void k_stats(const float* __restrict__ Y,
                                               float* __restrict__ sum,
                                               float* __restrict__ sq) {
    int f = threadIdx.x & 127;
    int half = threadIdx.x >> 7;
    float s = 0.f, q = 0.f;
    for (long r = (long)blockIdx.x * 2 + half; r < NN; r += (long)gridDim.x * 2) {
        float v = Y[r * D + f];
        s += v;
        q += v * v;
    }
    atomicAdd(sum + f, s);
    atomicAdd(sq + f, q);
}

__global__ void k_fin1(const float* __restrict__ sum, const float* __restrict__ sq,
                       const float* __restrict__ g1, const float* __restrict__ bt1,
                       const float* __restrict__ b2, float* __restrict__ a1,
                       float* __restrict__ c1, float* __restrict__ biasF) {
    int f = threadIdx.x;
    float m = sum[f] * (1.f / NN);
    float v = sq[f] * (1.f / NN) - m * m;
    float a = g1[f] * rsqrtf(v + EPS);
    a1[f] = a;
    c1[f] = bt1[f] - m * a;
    biasF[f] = b2[f];
}

__global__ __launch_bounds__(128) void k_fold(const float* __restrict__ W2,
                                              const float* __restrict__ a1,
                                              const float* __restrict__ c1,
                                              float* __restrict__ W2s,
                                              float* __restrict__ biasF) {
    int k = blockIdx.x, j = threadIdx.x;
    float w = W2[(long)k * 128 + j];
    W2s[(long)k * 128 + j] = a1[k] * w;
    atomicAdd(biasF + j, c1[k] * w);
}

__global__ void k_fin2(const float* __restrict__ sum, const float* __restrict__ sq,
                       const float* __restrict__ g2, const float* __restrict__ go,
                       const float* __restrict__ bo, float* __restrict__ affA,
                       float* __restrict__ affB) {
    int f = threadIdx.x;
    float m = sum[f] * (1.f / NN);
    float v = sq[f] * (1.f / NN) - m * m;
    float t = g2[f] * rsqrtf(v + EPS);
    float vo = t * t * v;
    float Aa = t * rsqrtf(vo + EPS) * go[f];
    affA[f] = Aa;
    affB[f] = bo[f] - m * Aa;
}

__global__ __launch_bounds__(256) void k_affine(const float4* __restrict__ Y,
                                                const float* __restrict__ affA,
                                                const float* __restrict__ affB,
                                                float4* __restrict__ o1) {
    const long n4 = (long)NN * 32;
    for (long i = (long)blockIdx.x * 256 + threadIdx.x; i < n4;
         i += (long)gridDim.x * 256) {
        int c4 = (int)(i & 31) * 4;
        float4 v = Y[i];
        float4 A = *(const float4*)(affA + c4);
        float4 B = *(const float4*)(affB + c4);
        float4 r;
        r.x = fmaxf(fmaf(v.x, A.x, B.x), 0.f);
        r.y = fmaxf(fmaf(v.y, A.y, B.y), 0.f);
        r.z = fmaxf(fmaf(v.z, A.z, B.z), 0.f);
        r.w = fmaxf(fmaf(v.w, A.w, B.w), 0.f);
        o1[i] = r;
    }
}

__device__ __forceinline__ int lower_bound_i(const int* __restrict__ a, int n, int v) {
    int lo = 0, hi = n;
    while (lo < hi) {
        int m = (lo + hi) >> 1;
        if (a[m] < v) lo = m + 1; else hi = m;
    }
    return lo;
}

__global__ __launch_bounds__(128) void k_pool(const float* __restrict__ h,
                                              const int* __restrict__ batch,
                                              const float* __restrict__ fcW,
                                              const float* __restrict__ fcb,
                                              float* __restrict__ ge,
                                              float* __restrict__ out) {
    __shared__ float r0[128], r1[128];
    int g = blockIdx.x, j = threadIdx.x;
    int lo = lower_bound_i(batch, NN, g);
    int hi = lower_bound_i(batch, NN, g + 1);
    float s = 0.f;
    for (int r = lo; r < hi; ++r) s += h[(long)r * D + j];
    int cnt = hi - lo;
    float mean = s / (float)(cnt > 0 ? cnt : 1);
    ge[(long)g * D + j] = mean;
    r0[j] = mean * fcW[j * 2 + 0];
    r1[j] = mean * fcW[j * 2 + 1];
    __syncthreads();
    for (int st = 64; st > 0; st >>= 1) {
        if (j < st) { r0[j] += r0[j + st]; r1[j] += r1[j + st]; }
        __syncthreads();
    }
    if (j == 0) {
        out[g * 2 + 0] = r0[0] + fcb[0];
        out[g * 2 + 1] = r1[0] + fcb[1];
    }
}

// ---------------------------------------------------------------------------
extern "C" void kernel_launch(void* const* d_in, const int* in_sizes, int n_in,
                              void* d_out, int out_size, void* d_ws, size_t ws_size,
                              hipStream_t stream) {
    const float* x   = (const float*)d_in[0];
    const int*   ei  = (const int*)d_in[1];
    const int*   bat = (const int*)d_in[2];
    const float* W1  = (const float*)d_in[3];
    const float* b1  = (const float*)d_in[4];
    const float* g1  = (const float*)d_in[5];
    const float* bt1 = (const float*)d_in[6];
    const float* W2  = (const float*)d_in[7];
    const float* b2  = (const float*)d_in[8];
    const float* g2  = (const float*)d_in[9];
    const float* go  = (const float*)d_in[11];
    const float* bo  = (const float*)d_in[12];
    const float* fcW = (const float*)d_in[13];
    const float* fcb = (const float*)d_in[14];

    const long ND = (long)NN * D;
    float* H = (float*)d_ws;
    float* G = H + ND;
    float* S = G + ND;
    float* sum   = S;
    float* sq    = S + 128;
    float* a1    = S + 256;
    float* c1    = S + 384;
    float* biasF = S + 512;
    float* affA  = S + 640;
    float* affB  = S + 768;
    float* W2s   = S + 1024;            // 128*128 floats
    int*   off   = (int*)(S + 1024 + 16384);  // NN+1 ints (persistent)
    int*   srcs  = off + (NN + 1);            // NE ints (persistent)

    float* nodeEmb = (float*)d_out;     // also GEMM1 scratch Y
    float* ge   = nodeEmb + ND;
    float* out2 = ge + (long)NG * D;
    float* Y = nodeEmb;

    // CSR-build temporaries alias into nodeEmb (free until first GEMM)
    int* deg  = (int*)nodeEmb;          // NN
    int* excl = deg + NN;               // NN
    int* cur  = excl + NN;              // NN
    int* bsum = cur + NN;               // 512

    const int edgeGrid = (NE + 255) / 256;       // 2344
    const int nodeGrid = (NN + 255) / 256;       // 391
    const int gathGrid = (int)(((long)NN * 32 + 255) / 256);  // 12500
    const int gemmGrid = (NN + BM - 1) / BM;     // 1563

    // ---- CSR build (once per call, reused by all 3 layers) ----
    hipMemsetAsync(deg, 0, NN * sizeof(int), stream);
    k_hist<<<edgeGrid, 256, 0, stream>>>(ei, deg);
    k_scan1<<<nodeGrid, 256, 0, stream>>>(deg, excl, bsum);
    k_scan2<<<1, 512, 0, stream>>>(bsum, nodeGrid);
    k_scan3<<<nodeGrid, 256, 0, stream>>>(excl, bsum, off, cur);
    k_fill<<<edgeGrid, 256, 0, stream>>>(ei, cur, srcs);

    for (int l = 0; l < NL; ++l) {
        const float* hin = (l == 0) ? x : H;
        k_gather<<<gathGrid, 256, 0, stream>>>((const float4*)hin, off, srcs,
                                               (float4*)G);

        hipMemsetAsync(sum, 0, 256 * sizeof(float), stream);
        k_gemm<<<gemmGrid, 256, 0, stream>>>(G, W1 + (long)l * D * D, b1 + l * D, Y);
        k_stats<<<512, 256, 0, stream>>>(Y, sum, sq);
        k_fin1<<<1, 128, 0, stream>>>(sum, sq, g1 + l * D, bt1 + l * D, b2 + l * D,
                                      a1, c1, biasF);
        k_fold<<<128, 128, 0, stream>>>(W2 + (long)l * D * D, a1, c1, W2s, biasF);

        hipMemsetAsync(sum, 0, 256 * sizeof(float), stream);
        k_gemm<<<gemmGrid, 256, 0, stream>>>(Y, W2s, biasF, G);
        k_stats<<<512, 256, 0, stream>>>(G, sum, sq);
        k_fin2<<<1, 128, 0, stream>>>(sum, sq, g2 + l * D, go + l * D, bo + l * D,
                                      affA, affB);

        float* o1 = (l == NL - 1) ? nodeEmb : H;
        k_affine<<<4096, 256, 0, stream>>>((const float4*)G, affA, affB, (float4*)o1);
    }

    k_pool<<<NG, 128, 0, stream>>>(nodeEmb, bat, fcW, fcb, ge, out2);
}

// Round 4
// 918.923 us; speedup vs baseline: 4.3375x; 1.2336x over previous
//
#include <hip/hip_runtime.h>

#define NN 100000
#define NE 600000
#define NG 512
#define D 128
#define NL 3
#define EPS 1e-5f

// ---------------------------------------------------------------------------
// CSR build: histogram -> exclusive scan -> fill (sorted-by-dst source list)
// ---------------------------------------------------------------------------
__global__ __launch_bounds__(256) void k_hist(const int* __restrict__ ei,
                                              int* __restrict__ deg) {
    int e = blockIdx.x * 256 + threadIdx.x;
    if (e < NE) atomicAdd(&deg[ei[NE + e]], 1);
}

__global__ __launch_bounds__(256) void k_scan1(const int* __restrict__ deg,
                                               int* __restrict__ excl,
                                               int* __restrict__ bsum) {
    __shared__ int s[256];
    int i = blockIdx.x * 256 + threadIdx.x;
    int v = (i < NN) ? deg[i] : 0;
    s[threadIdx.x] = v;
    __syncthreads();
    #pragma unroll
    for (int st = 1; st < 256; st <<= 1) {
        int t = (threadIdx.x >= st) ? s[threadIdx.x - st] : 0;
        __syncthreads();
        s[threadIdx.x] += t;
        __syncthreads();
    }
    if (i < NN) excl[i] = s[threadIdx.x] - v;
    if (threadIdx.x == 255) bsum[blockIdx.x] = s[255];
}

__global__ __launch_bounds__(512) void k_scan2(int* __restrict__ bsum, int nb) {
    __shared__ int s[512];
    int v = (threadIdx.x < nb) ? bsum[threadIdx.x] : 0;
    s[threadIdx.x] = v;
    __syncthreads();
    #pragma unroll
    for (int st = 1; st < 512; st <<= 1) {
        int t = (threadIdx.x >= st) ? s[threadIdx.x - st] : 0;
        __syncthreads();
        s[threadIdx.x] += t;
        __syncthreads();
    }
    if (threadIdx.x < nb) bsum[threadIdx.x] = s[threadIdx.x] - v;  // exclusive
}

__global__ __launch_bounds__(256) void k_scan3(const int* __restrict__ excl,
                                               const int* __restrict__ bsum,
                                               int* __restrict__ off,
                                               int* __restrict__ cur) {
    int i = blockIdx.x * 256 + threadIdx.x;
    if (i < NN) {
        int o = excl[i] + bsum[blockIdx.x];
        off[i] = o;
        cur[i] = o;
    }
    if (i == 0) off[NN] = NE;
}

__global__ __launch_bounds__(256) void k_fill(const int* __restrict__ ei,
                                              int* __restrict__ cur,
                                              int* __restrict__ srcs) {
    int e = blockIdx.x * 256 + threadIdx.x;
    if (e < NE) {
        int d = ei[NE + e];
        int p = atomicAdd(&cur[d], 1);
        srcs[p] = ei[e];
    }
}

// ---------------------------------------------------------------------------
// Gather aggregation (layer 0): G[n] = x[n] + sum_{s in N_in(n)} x[s]
// ---------------------------------------------------------------------------
__global__ __launch_bounds__(256) void k_gather(const float4* __restrict__ hin,
                                                const int* __restrict__ off,
                                                const int* __restrict__ srcs,
                                                float4* __restrict__ g) {
    int t = blockIdx.x * 256 + threadIdx.x;
    int n = t >> 5;
    if (n >= NN) return;
    int f4 = t & 31;
    int lo = off[n], hi = off[n + 1];
    float4 acc = hin[(long)n * 32 + f4];
    for (int e = lo; e < hi; ++e) {
        int s = srcs[e];
        float4 v = hin[(long)s * 32 + f4];
        acc.x += v.x; acc.y += v.y; acc.z += v.z; acc.w += v.w;
    }
    g[(long)n * 32 + f4] = acc;
}

// Gather with fused affine+ReLU (layers 1,2): h = relu(y2*A+B) applied on the fly.
__global__ __launch_bounds__(256) void k_gather_aff(const float4* __restrict__ yin,
                                                    const int* __restrict__ off,
                                                    const int* __restrict__ srcs,
                                                    const float* __restrict__ affA,
                                                    const float* __restrict__ affB,
                                                    float4* __restrict__ g) {
    int t = blockIdx.x * 256 + threadIdx.x;
    int n = t >> 5;
    if (n >= NN) return;
    int f4 = t & 31;
    float4 A = *(const float4*)(affA + f4 * 4);
    float4 B = *(const float4*)(affB + f4 * 4);
    int lo = off[n], hi = off[n + 1];
    float4 v = yin[(long)n * 32 + f4];
    float4 acc;
    acc.x = fmaxf(fmaf(v.x, A.x, B.x), 0.f);
    acc.y = fmaxf(fmaf(v.y, A.y, B.y), 0.f);
    acc.z = fmaxf(fmaf(v.z, A.z, B.z), 0.f);
    acc.w = fmaxf(fmaf(v.w, A.w, B.w), 0.f);
    for (int e = lo; e < hi; ++e) {
        int s = srcs[e];
        float4 u = yin[(long)s * 32 + f4];
        acc.x += fmaxf(fmaf(u.x, A.x, B.x), 0.f);
        acc.y += fmaxf(fmaf(u.y, A.y, B.y), 0.f);
        acc.z += fmaxf(fmaf(u.z, A.z, B.z), 0.f);
        acc.w += fmaxf(fmaf(u.w, A.w, B.w), 0.f);
    }
    g[(long)n * 32 + f4] = acc;
}

// ---------------------------------------------------------------------------
// fp32 GEMM + fused column stats:
//   C[M x 128] = A[M x 128] @ W[128 x 128] + bias ; sum[c]+=..., sq[c]+=...
// BM=128 rows/block, 256 threads, 8x8 micro-tile. Per-BK chunk staging:
//   Ws [32][128] quad-permuted (reads 2-way/free), reused post-loop for stats
//   AsT [32][129] transposed+pad (writes 2-way, reads broadcast)
// 32.9 KB LDS -> 4 blocks/CU = 16 waves/CU.
// ---------------------------------------------------------------------------
#define BM 128
#define BK 32
#define RST 129

__global__ __launch_bounds__(256, 4) void k_gemm(const float* __restrict__ A,
                                                 const float* __restrict__ W,
                                                 const float* __restrict__ bias,
                                                 float* __restrict__ C,
                                                 float* __restrict__ sum,
                                                 float* __restrict__ sq) {
    __shared__ float Ws[BK * 128];   // 4096 floats; reused as stats scratch
    __shared__ float As[BK * RST];
    const int tid = threadIdx.x;
    const int ty = tid >> 4;   // 0..15 -> rows ty*8..+7
    const int tx = tid & 15;   // 0..15 -> cols tx*8..+7
    const long base = (long)blockIdx.x * BM;

    float acc[8][8];
    #pragma unroll
    for (int i = 0; i < 8; ++i)
        #pragma unroll
        for (int c = 0; c < 8; ++c) acc[i][c] = 0.f;

    for (int kc = 0; kc < 128; kc += BK) {
        // stage W chunk with quad permutation p(q) = (q&1)*16 + (q>>1)
        #pragma unroll
        for (int j = 0; j < 4; ++j) {
            int e = tid + j * 256;
            int k = e >> 5, q = e & 31;
            int p = ((q & 1) << 4) + (q >> 1);
            float4 v = *(const float4*)(W + (long)(kc + k) * 128 + q * 4);
            *(float4*)(&Ws[k * 128 + p * 4]) = v;
        }
        // stage A chunk transposed: As[k][row]
        #pragma unroll
        for (int j = 0; j < 4; ++j) {
            int e = tid + j * 256;
            int row = e >> 3, cq = e & 7;
            long gr = base + row;
            float4 v = make_float4(0.f, 0.f, 0.f, 0.f);
            if (gr < NN) v = *(const float4*)(A + gr * D + kc + cq * 4);
            As[(cq * 4 + 0) * RST + row] = v.x;
            As[(cq * 4 + 1) * RST + row] = v.y;
            As[(cq * 4 + 2) * RST + row] = v.z;
            As[(cq * 4 + 3) * RST + row] = v.w;
        }
        __syncthreads();
        #pragma unroll
        for (int k = 0; k < BK; ++k) {
            float4 a0 = *(const float4*)(&As[k * RST + ty * 8]);
            float4 a1 = *(const float4*)(&As[k * RST + ty * 8 + 4]);
            float4 w0 = *(const float4*)(&Ws[k * 128 + tx * 4]);
            float4 w1 = *(const float4*)(&Ws[k * 128 + 64 + tx * 4]);
            float av[8] = {a0.x, a0.y, a0.z, a0.w, a1.x, a1.y, a1.z, a1.w};
            float wv[8] = {w0.x, w0.y, w0.z, w0.w, w1.x, w1.y, w1.z, w1.w};
            #pragma unroll
            for (int i = 0; i < 8; ++i)
                #pragma unroll
                for (int c = 0; c < 8; ++c) acc[i][c] = fmaf(av[i], wv[c], acc[i][c]);
        }
        __syncthreads();
    }

    float4 b0 = *(const float4*)(bias + tx * 8);
    float4 b1 = *(const float4*)(bias + tx * 8 + 4);
    float bv[8] = {b0.x, b0.y, b0.z, b0.w, b1.x, b1.y, b1.z, b1.w};
    float csum[8], csq[8];
    #pragma unroll
    for (int c = 0; c < 8; ++c) { csum[c] = 0.f; csq[c] = 0.f; }
    #pragma unroll
    for (int i = 0; i < 8; ++i) {
        long gr = base + ty * 8 + i;
        if (gr < NN) {
            float o[8];
            #pragma unroll
            for (int c = 0; c < 8; ++c) {
                o[c] = acc[i][c] + bv[c];
                csum[c] += o[c];
                csq[c] += o[c] * o[c];
            }
            *(float4*)(C + gr * D + tx * 8) = make_float4(o[0], o[1], o[2], o[3]);
            *(float4*)(C + gr * D + tx * 8 + 4) = make_float4(o[4], o[5], o[6], o[7]);
        }
    }
    // block-level stats reduction in LDS (reuse Ws: 2048 sum + 2048 sq floats)
    float* red = Ws;
    *(float4*)(&red[ty * 128 + tx * 8]) = make_float4(csum[0], csum[1], csum[2], csum[3]);
    *(float4*)(&red[ty * 128 + tx * 8 + 4]) = make_float4(csum[4], csum[5], csum[6], csum[7]);
    *(float4*)(&red[2048 + ty * 128 + tx * 8]) = make_float4(csq[0], csq[1], csq[2], csq[3]);
    *(float4*)(&red[2048 + ty * 128 + tx * 8 + 4]) = make_float4(csq[4], csq[5], csq[6], csq[7]);
    __syncthreads();
    if (tid < 128) {
        float t = 0.f;
        #pragma unroll
        for (int j = 0; j < 16; ++j) t += red[j * 128 + tid];
        atomicAdd(sum + tid, t);
    } else {
        int col = tid - 128;
        float t = 0.f;
        #pragma unroll
        for (int j = 0; j < 16; ++j) t += red[2048 + j * 128 + col];
        atomicAdd(sq + col, t);
    }
}

// ---------------------------------------------------------------------------
// Fused BN1-finalize + fold into GEMM2 operands (biasF pre-initialized to b2):
//   a1[k]=g1[k]*rsqrt(v+eps), c1[k]=bt1[k]-m*a1[k]
//   W2s[k][j] = a1[k]*W2[k][j]; biasF[j] += c1[k]*W2[k][j]
// ---------------------------------------------------------------------------
__global__ __launch_bounds__(128) void k_fold(const float* __restrict__ W2,
                                              const float* __restrict__ sum,
                                              const float* __restrict__ sq,
                                              const float* __restrict__ g1,
                                              const float* __restrict__ bt1,
                                              float* __restrict__ W2s,
                                              float* __restrict__ biasF) {
    int k = blockIdx.x, j = threadIdx.x;
    float m = sum[k] * (1.f / NN);
    float v = sq[k] * (1.f / NN) - m * m;
    float a = g1[k] * rsqrtf(v + EPS);
    float c = bt1[k] - m * a;
    float w = W2[(long)k * 128 + j];
    W2s[(long)k * 128 + j] = a * w;
    atomicAdd(biasF + j, c * w);
}

// BN2 + outer BN collapse: A = rs2*g2*rso*go, B = bo - m2*A
__global__ void k_fin2(const float* __restrict__ sum, const float* __restrict__ sq,
                       const float* __restrict__ g2, const float* __restrict__ go,
                       const float* __restrict__ bo, float* __restrict__ affA,
                       float* __restrict__ affB) {
    int f = threadIdx.x;
    float m = sum[f] * (1.f / NN);
    float v = sq[f] * (1.f / NN) - m * m;
    float t = g2[f] * rsqrtf(v + EPS);
    float vo = t * t * v;
    float Aa = t * rsqrtf(vo + EPS) * go[f];
    affA[f] = Aa;
    affB[f] = bo[f] - m * Aa;
}

// Final-layer affine+ReLU materializing nodeEmb
__global__ __launch_bounds__(256) void k_affine(const float4* __restrict__ Y,
                                                const float* __restrict__ affA,
                                                const float* __restrict__ affB,
                                                float4* __restrict__ o1) {
    const long n4 = (long)NN * 32;
    for (long i = (long)blockIdx.x * 256 + threadIdx.x; i < n4;
         i += (long)gridDim.x * 256) {
        int c4 = (int)(i & 31) * 4;
        float4 v = Y[i];
        float4 A = *(const float4*)(affA + c4);
        float4 B = *(const float4*)(affB + c4);
        float4 r;
        r.x = fmaxf(fmaf(v.x, A.x, B.x), 0.f);
        r.y = fmaxf(fmaf(v.y, A.y, B.y), 0.f);
        r.z = fmaxf(fmaf(v.z, A.z, B.z), 0.f);
        r.w = fmaxf(fmaf(v.w, A.w, B.w), 0.f);
        o1[i] = r;
    }
}

__device__ __forceinline__ int lower_bound_i(const int* __restrict__ a, int n, int v) {
    int lo = 0, hi = n;
    while (lo < hi) {
        int m = (lo + hi) >> 1;
        if (a[m] < v) lo = m + 1; else hi = m;
    }
    return lo;
}

__global__ __launch_bounds__(128) void k_pool(const float* __restrict__ h,
                                              const int* __restrict__ batch,
                                              const float* __restrict__ fcW,
                                              const float* __restrict__ fcb,
                                              float* __restrict__ ge,
                                              float* __restrict__ out) {
    __shared__ float r0[128], r1[128];
    int g = blockIdx.x, j = threadIdx.x;
    int lo = lower_bound_i(batch, NN, g);
    int hi = lower_bound_i(batch, NN, g + 1);
    float s = 0.f;
    for (int r = lo; r < hi; ++r) s += h[(long)r * D + j];
    int cnt = hi - lo;
    float mean = s / (float)(cnt > 0 ? cnt : 1);
    ge[(long)g * D + j] = mean;
    r0[j] = mean * fcW[j * 2 + 0];
    r1[j] = mean * fcW[j * 2 + 1];
    __syncthreads();
    for (int st = 64; st > 0; st >>= 1) {
        if (j < st) { r0[j] += r0[j + st]; r1[j] += r1[j + st]; }
        __syncthreads();
    }
    if (j == 0) {
        out[g * 2 + 0] = r0[0] + fcb[0];
        out[g * 2 + 1] = r1[0] + fcb[1];
    }
}

// ---------------------------------------------------------------------------
extern "C" void kernel_launch(void* const* d_in, const int* in_sizes, int n_in,
                              void* d_out, int out_size, void* d_ws, size_t ws_size,
                              hipStream_t stream) {
    const float* x   = (const float*)d_in[0];
    const int*   ei  = (const int*)d_in[1];
    const int*   bat = (const int*)d_in[2];
    const float* W1  = (const float*)d_in[3];
    const float* b1  = (const float*)d_in[4];
    const float* g1  = (const float*)d_in[5];
    const float* bt1 = (const float*)d_in[6];
    const float* W2  = (const float*)d_in[7];
    const float* b2  = (const float*)d_in[8];
    const float* g2  = (const float*)d_in[9];
    const float* go  = (const float*)d_in[11];
    const float* bo  = (const float*)d_in[12];
    const float* fcW = (const float*)d_in[13];
    const float* fcb = (const float*)d_in[14];

    const long ND = (long)NN * D;
    float* H = (float*)d_ws;
    float* G = H + ND;
    float* S = G + ND;
    float* sum   = S;
    float* sq    = S + 128;
    float* biasF = S + 512;
    float* affA  = S + 640;
    float* affB  = S + 768;
    float* W2s   = S + 1024;                  // 128*128 floats
    int*   off   = (int*)(S + 1024 + 16384);  // NN+1 ints
    int*   srcs  = off + (NN + 1);            // NE ints

    float* nodeEmb = (float*)d_out;     // also GEMM1 scratch Y
    float* ge   = nodeEmb + ND;
    float* out2 = ge + (long)NG * D;
    float* Y = nodeEmb;

    // CSR-build temporaries alias into nodeEmb (consumed before first GEMM)
    int* deg  = (int*)nodeEmb;
    int* excl = deg + NN;
    int* cur  = excl + NN;
    int* bsum = cur + NN;

    const int edgeGrid = (NE + 255) / 256;
    const int nodeGrid = (NN + 255) / 256;
    const int gathGrid = (int)(((long)NN * 32 + 255) / 256);
    const int gemmGrid = (NN + BM - 1) / BM;   // 782

    hipMemsetAsync(deg, 0, NN * sizeof(int), stream);
    k_hist<<<edgeGrid, 256, 0, stream>>>(ei, deg);
    k_scan1<<<nodeGrid, 256, 0, stream>>>(deg, excl, bsum);
    k_scan2<<<1, 512, 0, stream>>>(bsum, nodeGrid);
    k_scan3<<<nodeGrid, 256, 0, stream>>>(excl, bsum, off, cur);
    k_fill<<<edgeGrid, 256, 0, stream>>>(ei, cur, srcs);

    for (int l = 0; l < NL; ++l) {
        if (l == 0)
            k_gather<<<gathGrid, 256, 0, stream>>>((const float4*)x, off, srcs,
                                                   (float4*)G);
        else
            k_gather_aff<<<gathGrid, 256, 0, stream>>>((const float4*)G, off, srcs,
                                                       affA, affB, (float4*)H);
        const float* gin = (l == 0) ? G : H;

        hipMemsetAsync(sum, 0, 256 * sizeof(float), stream);
        k_gemm<<<gemmGrid, 256, 0, stream>>>(gin, W1 + (long)l * D * D, b1 + l * D,
                                             Y, sum, sq);
        hipMemcpyAsync(biasF, b2 + (long)l * D, D * sizeof(float),
                       hipMemcpyDeviceToDevice, stream);
        k_fold<<<128, 128, 0, stream>>>(W2 + (long)l * D * D, sum, sq,
                                        g1 + l * D, bt1 + l * D, W2s, biasF);

        hipMemsetAsync(sum, 0, 256 * sizeof(float), stream);
        k_gemm<<<gemmGrid, 256, 0, stream>>>(Y, W2s, biasF, G, sum, sq);
        k_fin2<<<1, 128, 0, stream>>>(sum, sq, g2 + l * D, go + l * D, bo + l * D,
                                      affA, affB);
    }

    k_affine<<<4096, 256, 0, stream>>>((const float4*)G, affA, affB,
                                       (float4*)nodeEmb);
    k_pool<<<NG, 128, 0, stream>>>(nodeEmb, bat, fcW, fcb, ge, out2);
}

// Round 5
// 858.564 us; speedup vs baseline: 4.6424x; 1.0703x over previous
//
#include <hip/hip_runtime.h>

#define NN 100000
#define NE 600000
#define NG 512
#define D 128
#define NL 3
#define EPS 1e-5f

// ---------------------------------------------------------------------------
// CSR build: histogram -> exclusive scan -> fill (sorted-by-dst source list)
// ---------------------------------------------------------------------------
__global__ __launch_bounds__(256) void k_hist(const int* __restrict__ ei,
                                              int* __restrict__ deg) {
    int e = blockIdx.x * 256 + threadIdx.x;
    if (e < NE) atomicAdd(&deg[ei[NE + e]], 1);
}

__global__ __launch_bounds__(256) void k_scan1(const int* __restrict__ deg,
                                               int* __restrict__ excl,
                                               int* __restrict__ bsum) {
    __shared__ int s[256];
    int i = blockIdx.x * 256 + threadIdx.x;
    int v = (i < NN) ? deg[i] : 0;
    s[threadIdx.x] = v;
    __syncthreads();
    #pragma unroll
    for (int st = 1; st < 256; st <<= 1) {
        int t = (threadIdx.x >= st) ? s[threadIdx.x - st] : 0;
        __syncthreads();
        s[threadIdx.x] += t;
        __syncthreads();
    }
    if (i < NN) excl[i] = s[threadIdx.x] - v;
    if (threadIdx.x == 255) bsum[blockIdx.x] = s[255];
}

__global__ __launch_bounds__(512) void k_scan2(int* __restrict__ bsum, int nb) {
    __shared__ int s[512];
    int v = (threadIdx.x < nb) ? bsum[threadIdx.x] : 0;
    s[threadIdx.x] = v;
    __syncthreads();
    #pragma unroll
    for (int st = 1; st < 512; st <<= 1) {
        int t = (threadIdx.x >= st) ? s[threadIdx.x - st] : 0;
        __syncthreads();
        s[threadIdx.x] += t;
        __syncthreads();
    }
    if (threadIdx.x < nb) bsum[threadIdx.x] = s[threadIdx.x] - v;  // exclusive
}

__global__ __launch_bounds__(256) void k_scan3(const int* __restrict__ excl,
                                               const int* __restrict__ bsum,
                                               int* __restrict__ off,
                                               int* __restrict__ cur) {
    int i = blockIdx.x * 256 + threadIdx.x;
    if (i < NN) {
        int o = excl[i] + bsum[blockIdx.x];
        off[i] = o;
        cur[i] = o;
    }
    if (i == 0) off[NN] = NE;
}

__global__ __launch_bounds__(256) void k_fill(const int* __restrict__ ei,
                                              int* __restrict__ cur,
                                              int* __restrict__ srcs) {
    int e = blockIdx.x * 256 + threadIdx.x;
    if (e < NE) {
        int d = ei[NE + e];
        int p = atomicAdd(&cur[d], 1);
        srcs[p] = ei[e];
    }
}

// ---------------------------------------------------------------------------
// Gather aggregation (layer 0): G[n] = x[n] + sum_{s in N_in(n)} x[s]
// ---------------------------------------------------------------------------
__global__ __launch_bounds__(256) void k_gather(const float4* __restrict__ hin,
                                                const int* __restrict__ off,
                                                const int* __restrict__ srcs,
                                                float4* __restrict__ g) {
    int t = blockIdx.x * 256 + threadIdx.x;
    int n = t >> 5;
    if (n >= NN) return;
    int f4 = t & 31;
    int lo = off[n], hi = off[n + 1];
    float4 acc = hin[(long)n * 32 + f4];
    for (int e = lo; e < hi; ++e) {
        int s = srcs[e];
        float4 v = hin[(long)s * 32 + f4];
        acc.x += v.x; acc.y += v.y; acc.z += v.z; acc.w += v.w;
    }
    g[(long)n * 32 + f4] = acc;
}

// Gather with fused affine+ReLU (layers 1,2): h = relu(y2*A+B) applied on the fly.
__global__ __launch_bounds__(256) void k_gather_aff(const float4* __restrict__ yin,
                                                    const int* __restrict__ off,
                                                    const int* __restrict__ srcs,
                                                    const float* __restrict__ affA,
                                                    const float* __restrict__ affB,
                                                    float4* __restrict__ g) {
    int t = blockIdx.x * 256 + threadIdx.x;
    int n = t >> 5;
    if (n >= NN) return;
    int f4 = t & 31;
    float4 A = *(const float4*)(affA + f4 * 4);
    float4 B = *(const float4*)(affB + f4 * 4);
    int lo = off[n], hi = off[n + 1];
    float4 v = yin[(long)n * 32 + f4];
    float4 acc;
    acc.x = fmaxf(fmaf(v.x, A.x, B.x), 0.f);
    acc.y = fmaxf(fmaf(v.y, A.y, B.y), 0.f);
    acc.z = fmaxf(fmaf(v.z, A.z, B.z), 0.f);
    acc.w = fmaxf(fmaf(v.w, A.w, B.w), 0.f);
    for (int e = lo; e < hi; ++e) {
        int s = srcs[e];
        float4 u = yin[(long)s * 32 + f4];
        acc.x += fmaxf(fmaf(u.x, A.x, B.x), 0.f);
        acc.y += fmaxf(fmaf(u.y, A.y, B.y), 0.f);
        acc.z += fmaxf(fmaf(u.z, A.z, B.z), 0.f);
        acc.w += fmaxf(fmaf(u.w, A.w, B.w), 0.f);
    }
    g[(long)n * 32 + f4] = acc;
}

// ---------------------------------------------------------------------------
// fp32 GEMM + fused column stats.
// BM=64 rows/block -> grid 1563 (6.1 blocks/CU offered). 256 threads, 4x8
// micro-tile. LDS: W chunk [32][128] quad-permuted (16 KB, 2-way/free reads)
// + AsT [32][65] (8.3 KB). 24.6 KB -> 5 blocks/CU with launch_bounds(256,5)
// = 20 waves/CU. Stats reduced in LDS (reuse Ws), 2 atomics/col/block.
// ---------------------------------------------------------------------------
#define BM 64
#define BK 32
#define RST 65

__global__ __launch_bounds__(256, 5) void k_gemm(const float* __restrict__ A,
                                                 const float* __restrict__ W,
                                                 const float* __restrict__ bias,
                                                 float* __restrict__ C,
                                                 float* __restrict__ sum,
                                                 float* __restrict__ sq) {
    __shared__ float Ws[BK * 128];   // 4096 floats; reused as stats scratch
    __shared__ float As[BK * RST];
    const int tid = threadIdx.x;
    const int ty = tid >> 4;   // 0..15 -> rows ty*4..+3
    const int tx = tid & 15;   // 0..15 -> cols tx*8..+7
    const long base = (long)blockIdx.x * BM;

    float acc[4][8];
    #pragma unroll
    for (int i = 0; i < 4; ++i)
        #pragma unroll
        for (int c = 0; c < 8; ++c) acc[i][c] = 0.f;

    for (int kc = 0; kc < 128; kc += BK) {
        // stage W chunk with quad permutation p(q) = (q&1)*16 + (q>>1)
        #pragma unroll
        for (int j = 0; j < 4; ++j) {
            int e = tid + j * 256;        // 0..1023 quads
            int k = e >> 5, q = e & 31;
            int p = ((q & 1) << 4) + (q >> 1);
            float4 v = *(const float4*)(W + (long)(kc + k) * 128 + q * 4);
            *(float4*)(&Ws[k * 128 + p * 4]) = v;
        }
        // stage A chunk transposed: As[k][row]
        #pragma unroll
        for (int j = 0; j < 2; ++j) {
            int e = tid + j * 256;        // 0..511 quads
            int row = e >> 3, cq = e & 7;
            long gr = base + row;
            float4 v = make_float4(0.f, 0.f, 0.f, 0.f);
            if (gr < NN) v = *(const float4*)(A + gr * D + kc + cq * 4);
            As[(cq * 4 + 0) * RST + row] = v.x;
            As[(cq * 4 + 1) * RST + row] = v.y;
            As[(cq * 4 + 2) * RST + row] = v.z;
            As[(cq * 4 + 3) * RST + row] = v.w;
        }
        __syncthreads();
        #pragma unroll
        for (int k = 0; k < BK; ++k) {
            float4 a4 = *(const float4*)(&As[k * RST + ty * 4]);
            // physical quad p holds logical quad: w cols tx*8..+7 = quads
            // {2tx, 2tx+1} -> p = {tx, 16+tx}
            float4 w0 = *(const float4*)(&Ws[k * 128 + tx * 4]);
            float4 w1 = *(const float4*)(&Ws[k * 128 + 64 + tx * 4]);
            float av[4] = {a4.x, a4.y, a4.z, a4.w};
            float wv[8] = {w0.x, w0.y, w0.z, w0.w, w1.x, w1.y, w1.z, w1.w};
            #pragma unroll
            for (int i = 0; i < 4; ++i)
                #pragma unroll
                for (int c = 0; c < 8; ++c) acc[i][c] = fmaf(av[i], wv[c], acc[i][c]);
        }
        __syncthreads();
    }

    float4 b0 = *(const float4*)(bias + tx * 8);
    float4 b1 = *(const float4*)(bias + tx * 8 + 4);
    float bv[8] = {b0.x, b0.y, b0.z, b0.w, b1.x, b1.y, b1.z, b1.w};
    float csum[8], csq[8];
    #pragma unroll
    for (int c = 0; c < 8; ++c) { csum[c] = 0.f; csq[c] = 0.f; }
    #pragma unroll
    for (int i = 0; i < 4; ++i) {
        long gr = base + ty * 4 + i;
        if (gr < NN) {
            float o[8];
            #pragma unroll
            for (int c = 0; c < 8; ++c) {
                o[c] = acc[i][c] + bv[c];
                csum[c] += o[c];
                csq[c] += o[c] * o[c];
            }
            *(float4*)(C + gr * D + tx * 8) = make_float4(o[0], o[1], o[2], o[3]);
            *(float4*)(C + gr * D + tx * 8 + 4) = make_float4(o[4], o[5], o[6], o[7]);
        }
    }
    // block-level stats reduction in LDS (reuse Ws: 2048 sum + 2048 sq floats)
    float* red = Ws;
    __syncthreads();   // ensure main-loop Ws reads are done before overwrite
    *(float4*)(&red[ty * 128 + tx * 8]) = make_float4(csum[0], csum[1], csum[2], csum[3]);
    *(float4*)(&red[ty * 128 + tx * 8 + 4]) = make_float4(csum[4], csum[5], csum[6], csum[7]);
    *(float4*)(&red[2048 + ty * 128 + tx * 8]) = make_float4(csq[0], csq[1], csq[2], csq[3]);
    *(float4*)(&red[2048 + ty * 128 + tx * 8 + 4]) = make_float4(csq[4], csq[5], csq[6], csq[7]);
    __syncthreads();
    if (tid < 128) {
        float t = 0.f;
        #pragma unroll
        for (int j = 0; j < 16; ++j) t += red[j * 128 + tid];
        atomicAdd(sum + tid, t);
    } else {
        int col = tid - 128;
        float t = 0.f;
        #pragma unroll
        for (int j = 0; j < 16; ++j) t += red[2048 + j * 128 + col];
        atomicAdd(sq + col, t);
    }
}

// ---------------------------------------------------------------------------
// Fused BN1-finalize + fold into GEMM2 operands (biasF pre-initialized to b2).
// Block k consumes sum[k]/sq[k] then zeroes them for the next GEMM.
// ---------------------------------------------------------------------------
__global__ __launch_bounds__(128) void k_fold(const float* __restrict__ W2,
                                              float* __restrict__ sum,
                                              float* __restrict__ sq,
                                              const float* __restrict__ g1,
                                              const float* __restrict__ bt1,
                                              float* __restrict__ W2s,
                                              float* __restrict__ biasF) {
    int k = blockIdx.x, j = threadIdx.x;
    float m = sum[k] * (1.f / NN);
    float v = sq[k] * (1.f / NN) - m * m;
    __syncthreads();
    if (j == 0) { sum[k] = 0.f; sq[k] = 0.f; }
    float a = g1[k] * rsqrtf(v + EPS);
    float c = bt1[k] - m * a;
    float w = W2[(long)k * 128 + j];
    W2s[(long)k * 128 + j] = a * w;
    atomicAdd(biasF + j, c * w);
}

// BN2 + outer BN collapse: A = rs2*g2*rso*go, B = bo - m2*A. Zeroes sum/sq.
__global__ void k_fin2(float* __restrict__ sum, float* __restrict__ sq,
                       const float* __restrict__ g2, const float* __restrict__ go,
                       const float* __restrict__ bo, float* __restrict__ affA,
                       float* __restrict__ affB) {
    int f = threadIdx.x;
    float m = sum[f] * (1.f / NN);
    float v = sq[f] * (1.f / NN) - m * m;
    sum[f] = 0.f;
    sq[f] = 0.f;
    float t = g2[f] * rsqrtf(v + EPS);
    float vo = t * t * v;
    float Aa = t * rsqrtf(vo + EPS) * go[f];
    affA[f] = Aa;
    affB[f] = bo[f] - m * Aa;
}

// Final-layer affine+ReLU materializing nodeEmb
__global__ __launch_bounds__(256) void k_affine(const float4* __restrict__ Y,
                                                const float* __restrict__ affA,
                                                const float* __restrict__ affB,
                                                float4* __restrict__ o1) {
    const long n4 = (long)NN * 32;
    for (long i = (long)blockIdx.x * 256 + threadIdx.x; i < n4;
         i += (long)gridDim.x * 256) {
        int c4 = (int)(i & 31) * 4;
        float4 v = Y[i];
        float4 A = *(const float4*)(affA + c4);
        float4 B = *(const float4*)(affB + c4);
        float4 r;
        r.x = fmaxf(fmaf(v.x, A.x, B.x), 0.f);
        r.y = fmaxf(fmaf(v.y, A.y, B.y), 0.f);
        r.z = fmaxf(fmaf(v.z, A.z, B.z), 0.f);
        r.w = fmaxf(fmaf(v.w, A.w, B.w), 0.f);
        o1[i] = r;
    }
}

__device__ __forceinline__ int lower_bound_i(const int* __restrict__ a, int n, int v) {
    int lo = 0, hi = n;
    while (lo < hi) {
        int m = (lo + hi) >> 1;
        if (a[m] < v) lo = m + 1; else hi = m;
    }
    return lo;
}

__global__ __launch_bounds__(128) void k_pool(const float* __restrict__ h,
                                              const int* __restrict__ batch,
                                              const float* __restrict__ fcW,
                                              const float* __restrict__ fcb,
                                              float* __restrict__ ge,
                                              float* __restrict__ out) {
    __shared__ float r0[128], r1[128];
    int g = blockIdx.x, j = threadIdx.x;
    int lo = lower_bound_i(batch, NN, g);
    int hi = lower_bound_i(batch, NN, g + 1);
    float s = 0.f;
    for (int r = lo; r < hi; ++r) s += h[(long)r * D + j];
    int cnt = hi - lo;
    float mean = s / (float)(cnt > 0 ? cnt : 1);
    ge[(long)g * D + j] = mean;
    r0[j] = mean * fcW[j * 2 + 0];
    r1[j] = mean * fcW[j * 2 + 1];
    __syncthreads();
    for (int st = 64; st > 0; st >>= 1) {
        if (j < st) { r0[j] += r0[j + st]; r1[j] += r1[j + st]; }
        __syncthreads();
    }
    if (j == 0) {
        out[g * 2 + 0] = r0[0] + fcb[0];
        out[g * 2 + 1] = r1[0] + fcb[1];
    }
}

// ---------------------------------------------------------------------------
extern "C" void kernel_launch(void* const* d_in, const int* in_sizes, int n_in,
                              void* d_out, int out_size, void* d_ws, size_t ws_size,
                              hipStream_t stream) {
    const float* x   = (const float*)d_in[0];
    const int*   ei  = (const int*)d_in[1];
    const int*   bat = (const int*)d_in[2];
    const float* W1  = (const float*)d_in[3];
    const float* b1  = (const float*)d_in[4];
    const float* g1  = (const float*)d_in[5];
    const float* bt1 = (const float*)d_in[6];
    const float* W2  = (const float*)d_in[7];
    const float* b2  = (const float*)d_in[8];
    const float* g2  = (const float*)d_in[9];
    const float* go  = (const float*)d_in[11];
    const float* bo  = (const float*)d_in[12];
    const float* fcW = (const float*)d_in[13];
    const float* fcb = (const float*)d_in[14];

    const long ND = (long)NN * D;
    float* H = (float*)d_ws;
    float* G = H + ND;
    float* S = G + ND;
    float* sum   = S;
    float* sq    = S + 128;
    float* biasF = S + 512;
    float* affA  = S + 640;
    float* affB  = S + 768;
    float* W2s   = S + 1024;                  // 128*128 floats
    int*   off   = (int*)(S + 1024 + 16384);  // NN+1 ints
    int*   srcs  = off + (NN + 1);            // NE ints

    float* nodeEmb = (float*)d_out;     // also GEMM1 scratch Y
    float* ge   = nodeEmb + ND;
    float* out2 = ge + (long)NG * D;
    float* Y = nodeEmb;

    // CSR-build temporaries alias into nodeEmb (consumed before first GEMM)
    int* deg  = (int*)nodeEmb;
    int* excl = deg + NN;
    int* cur  = excl + NN;
    int* bsum = cur + NN;

    const int edgeGrid = (NE + 255) / 256;
    const int nodeGrid = (NN + 255) / 256;
    const int gathGrid = (int)(((long)NN * 32 + 255) / 256);
    const int gemmGrid = (NN + BM - 1) / BM;   // 1563

    hipMemsetAsync(deg, 0, NN * sizeof(int), stream);
    k_hist<<<edgeGrid, 256, 0, stream>>>(ei, deg);
    k_scan1<<<nodeGrid, 256, 0, stream>>>(deg, excl, bsum);
    k_scan2<<<1, 512, 0, stream>>>(bsum, nodeGrid);
    k_scan3<<<nodeGrid, 256, 0, stream>>>(excl, bsum, off, cur);
    k_fill<<<edgeGrid, 256, 0, stream>>>(ei, cur, srcs);

    // zero sum/sq once; consumers (k_fold/k_fin2) re-zero for the next GEMM
    hipMemsetAsync(sum, 0, 256 * sizeof(float), stream);

    for (int l = 0; l < NL; ++l) {
        if (l == 0)
            k_gather<<<gathGrid, 256, 0, stream>>>((const float4*)x, off, srcs,
                                                   (float4*)G);
        else
            k_gather_aff<<<gathGrid, 256, 0, stream>>>((const float4*)G, off, srcs,
                                                       affA, affB, (float4*)H);
        const float* gin = (l == 0) ? G : H;

        k_gemm<<<gemmGrid, 256, 0, stream>>>(gin, W1 + (long)l * D * D, b1 + l * D,
                                             Y, sum, sq);
        hipMemcpyAsync(biasF, b2 + (long)l * D, D * sizeof(float),
                       hipMemcpyDeviceToDevice, stream);
        k_fold<<<128, 128, 0, stream>>>(W2 + (long)l * D * D, sum, sq,
                                        g1 + l * D, bt1 + l * D, W2s, biasF);

        k_gemm<<<gemmGrid, 256, 0, stream>>>(Y, W2s, biasF, G, sum, sq);
        k_fin2<<<1, 128, 0, stream>>>(sum, sq, g2 + l * D, go + l * D, bo + l * D,
                                      affA, affB);
    }

    k_affine<<<4096, 256, 0, stream>>>((const float4*)G, affA, affB,
                                       (float4*)nodeEmb);
    k_pool<<<NG, 128, 0, stream>>>(nodeEmb, bat, fcW, fcb, ge, out2);
}

// Round 6
// 794.825 us; speedup vs baseline: 5.0147x; 1.0802x over previous
//
#include <hip/hip_runtime.h>

#define NN 100000
#define NE 600000
#define NG 512
#define D 128
#define NL 3
#define EPS 1e-5f

// ---------------------------------------------------------------------------
// CSR build: histogram -> exclusive scan -> fill (sorted-by-dst source list)
// ---------------------------------------------------------------------------
__global__ __launch_bounds__(256) void k_hist(const int* __restrict__ ei,
                                              int* __restrict__ deg) {
    int e = blockIdx.x * 256 + threadIdx.x;
    if (e < NE) atomicAdd(&deg[ei[NE + e]], 1);
}

__global__ __launch_bounds__(256) void k_scan1(const int* __restrict__ deg,
                                               int* __restrict__ excl,
                                               int* __restrict__ bsum) {
    __shared__ int s[256];
    int i = blockIdx.x * 256 + threadIdx.x;
    int v = (i < NN) ? deg[i] : 0;
    s[threadIdx.x] = v;
    __syncthreads();
    #pragma unroll
    for (int st = 1; st < 256; st <<= 1) {
        int t = (threadIdx.x >= st) ? s[threadIdx.x - st] : 0;
        __syncthreads();
        s[threadIdx.x] += t;
        __syncthreads();
    }
    if (i < NN) excl[i] = s[threadIdx.x] - v;
    if (threadIdx.x == 255) bsum[blockIdx.x] = s[255];
}

__global__ __launch_bounds__(512) void k_scan2(int* __restrict__ bsum, int nb) {
    __shared__ int s[512];
    int v = (threadIdx.x < nb) ? bsum[threadIdx.x] : 0;
    s[threadIdx.x] = v;
    __syncthreads();
    #pragma unroll
    for (int st = 1; st < 512; st <<= 1) {
        int t = (threadIdx.x >= st) ? s[threadIdx.x - st] : 0;
        __syncthreads();
        s[threadIdx.x] += t;
        __syncthreads();
    }
    if (threadIdx.x < nb) bsum[threadIdx.x] = s[threadIdx.x] - v;  // exclusive
}

__global__ __launch_bounds__(256) void k_scan3(const int* __restrict__ excl,
                                               const int* __restrict__ bsum,
                                               int* __restrict__ off,
                                               int* __restrict__ cur) {
    int i = blockIdx.x * 256 + threadIdx.x;
    if (i < NN) {
        int o = excl[i] + bsum[blockIdx.x];
        off[i] = o;
        cur[i] = o;
    }
    if (i == 0) off[NN] = NE;
}

__global__ __launch_bounds__(256) void k_fill(const int* __restrict__ ei,
                                              int* __restrict__ cur,
                                              int* __restrict__ srcs) {
    int e = blockIdx.x * 256 + threadIdx.x;
    if (e < NE) {
        int d = ei[NE + e];
        int p = atomicAdd(&cur[d], 1);
        srcs[p] = ei[e];
    }
}

// ---------------------------------------------------------------------------
// Graph offsets from sorted batch via boundary scan (no binary searches),
// plus per-layer biasF init (biasFall[l*128+j] = b2[l*128+j]).
// ---------------------------------------------------------------------------
__global__ __launch_bounds__(256) void k_goff(const int* __restrict__ batch,
                                              int* __restrict__ goff,
                                              const float* __restrict__ b2all,
                                              float* __restrict__ biasFall) {
    int i = blockIdx.x * 256 + threadIdx.x;
    if (blockIdx.x == 0) {
        for (int j = threadIdx.x; j < NL * D; j += 256) biasFall[j] = b2all[j];
    }
    if (i == 0) {
        int b0 = batch[0];
        for (int g = 0; g <= b0; ++g) goff[g] = 0;
    }
    if (i < NN - 1) {
        int b = batch[i], bn = batch[i + 1];
        for (int g = b + 1; g <= bn; ++g) goff[g] = i + 1;
    }
    if (i == NN - 1) {
        int b = batch[NN - 1];
        for (int g = b + 1; g <= NG; ++g) goff[g] = NN;
    }
}

// ---------------------------------------------------------------------------
// Gather aggregation (layer 0): G[n] = x[n] + sum_{s in N_in(n)} x[s]
// ---------------------------------------------------------------------------
__global__ __launch_bounds__(256) void k_gather(const float4* __restrict__ hin,
                                                const int* __restrict__ off,
                                                const int* __restrict__ srcs,
                                                float4* __restrict__ g) {
    int t = blockIdx.x * 256 + threadIdx.x;
    int n = t >> 5;
    if (n >= NN) return;
    int f4 = t & 31;
    int lo = off[n], hi = off[n + 1];
    float4 acc = hin[(long)n * 32 + f4];
    for (int e = lo; e < hi; ++e) {
        int s = srcs[e];
        float4 v = hin[(long)s * 32 + f4];
        acc.x += v.x; acc.y += v.y; acc.z += v.z; acc.w += v.w;
    }
    g[(long)n * 32 + f4] = acc;
}

// Gather with fused affine+ReLU (layers 1,2): h = relu(y2*A+B) applied on the fly.
__global__ __launch_bounds__(256) void k_gather_aff(const float4* __restrict__ yin,
                                                    const int* __restrict__ off,
                                                    const int* __restrict__ srcs,
                                                    const float* __restrict__ affA,
                                                    const float* __restrict__ affB,
                                                    float4* __restrict__ g) {
    int t = blockIdx.x * 256 + threadIdx.x;
    int n = t >> 5;
    if (n >= NN) return;
    int f4 = t & 31;
    float4 A = *(const float4*)(affA + f4 * 4);
    float4 B = *(const float4*)(affB + f4 * 4);
    int lo = off[n], hi = off[n + 1];
    float4 v = yin[(long)n * 32 + f4];
    float4 acc;
    acc.x = fmaxf(fmaf(v.x, A.x, B.x), 0.f);
    acc.y = fmaxf(fmaf(v.y, A.y, B.y), 0.f);
    acc.z = fmaxf(fmaf(v.z, A.z, B.z), 0.f);
    acc.w = fmaxf(fmaf(v.w, A.w, B.w), 0.f);
    for (int e = lo; e < hi; ++e) {
        int s = srcs[e];
        float4 u = yin[(long)s * 32 + f4];
        acc.x += fmaxf(fmaf(u.x, A.x, B.x), 0.f);
        acc.y += fmaxf(fmaf(u.y, A.y, B.y), 0.f);
        acc.z += fmaxf(fmaf(u.z, A.z, B.z), 0.f);
        acc.w += fmaxf(fmaf(u.w, A.w, B.w), 0.f);
    }
    g[(long)n * 32 + f4] = acc;
}

// ---------------------------------------------------------------------------
// fp32 GEMM + fused column stats. BM=64 (grid 1563), BK=32, 4x8 micro-tile.
// W chunk quad-permuted (2-way/free reads), AsT [32][65]. 24.6 KB LDS ->
// 5 blocks/CU = 20 waves/CU. Stats LDS-reduced, 2 atomics/col/block.
// ---------------------------------------------------------------------------
#define BM 64
#define BK 32
#define RST 65

__global__ __launch_bounds__(256, 5) void k_gemm(const float* __restrict__ A,
                                                 const float* __restrict__ W,
                                                 const float* __restrict__ bias,
                                                 float* __restrict__ C,
                                                 float* __restrict__ sum,
                                                 float* __restrict__ sq) {
    __shared__ float Ws[BK * 128];   // 4096 floats; reused as stats scratch
    __shared__ float As[BK * RST];
    const int tid = threadIdx.x;
    const int ty = tid >> 4;   // 0..15 -> rows ty*4..+3
    const int tx = tid & 15;   // 0..15 -> cols tx*8..+7
    const long base = (long)blockIdx.x * BM;

    float acc[4][8];
    #pragma unroll
    for (int i = 0; i < 4; ++i)
        #pragma unroll
        for (int c = 0; c < 8; ++c) acc[i][c] = 0.f;

    for (int kc = 0; kc < 128; kc += BK) {
        #pragma unroll
        for (int j = 0; j < 4; ++j) {
            int e = tid + j * 256;
            int k = e >> 5, q = e & 31;
            int p = ((q & 1) << 4) + (q >> 1);
            float4 v = *(const float4*)(W + (long)(kc + k) * 128 + q * 4);
            *(float4*)(&Ws[k * 128 + p * 4]) = v;
        }
        #pragma unroll
        for (int j = 0; j < 2; ++j) {
            int e = tid + j * 256;
            int row = e >> 3, cq = e & 7;
            long gr = base + row;
            float4 v = make_float4(0.f, 0.f, 0.f, 0.f);
            if (gr < NN) v = *(const float4*)(A + gr * D + kc + cq * 4);
            As[(cq * 4 + 0) * RST + row] = v.x;
            As[(cq * 4 + 1) * RST + row] = v.y;
            As[(cq * 4 + 2) * RST + row] = v.z;
            As[(cq * 4 + 3) * RST + row] = v.w;
        }
        __syncthreads();
        #pragma unroll
        for (int k = 0; k < BK; ++k) {
            float4 a4 = *(const float4*)(&As[k * RST + ty * 4]);
            float4 w0 = *(const float4*)(&Ws[k * 128 + tx * 4]);
            float4 w1 = *(const float4*)(&Ws[k * 128 + 64 + tx * 4]);
            float av[4] = {a4.x, a4.y, a4.z, a4.w};
            float wv[8] = {w0.x, w0.y, w0.z, w0.w, w1.x, w1.y, w1.z, w1.w};
            #pragma unroll
            for (int i = 0; i < 4; ++i)
                #pragma unroll
                for (int c = 0; c < 8; ++c) acc[i][c] = fmaf(av[i], wv[c], acc[i][c]);
        }
        __syncthreads();
    }

    float4 b0 = *(const float4*)(bias + tx * 8);
    float4 b1 = *(const float4*)(bias + tx * 8 + 4);
    float bv[8] = {b0.x, b0.y, b0.z, b0.w, b1.x, b1.y, b1.z, b1.w};
    float csum[8], csq[8];
    #pragma unroll
    for (int c = 0; c < 8; ++c) { csum[c] = 0.f; csq[c] = 0.f; }
    #pragma unroll
    for (int i = 0; i < 4; ++i) {
        long gr = base + ty * 4 + i;
        if (gr < NN) {
            float o[8];
            #pragma unroll
            for (int c = 0; c < 8; ++c) {
                o[c] = acc[i][c] + bv[c];
                csum[c] += o[c];
                csq[c] += o[c] * o[c];
            }
            *(float4*)(C + gr * D + tx * 8) = make_float4(o[0], o[1], o[2], o[3]);
            *(float4*)(C + gr * D + tx * 8 + 4) = make_float4(o[4], o[5], o[6], o[7]);
        }
    }
    float* red = Ws;
    __syncthreads();
    *(float4*)(&red[ty * 128 + tx * 8]) = make_float4(csum[0], csum[1], csum[2], csum[3]);
    *(float4*)(&red[ty * 128 + tx * 8 + 4]) = make_float4(csum[4], csum[5], csum[6], csum[7]);
    *(float4*)(&red[2048 + ty * 128 + tx * 8]) = make_float4(csq[0], csq[1], csq[2], csq[3]);
    *(float4*)(&red[2048 + ty * 128 + tx * 8 + 4]) = make_float4(csq[4], csq[5], csq[6], csq[7]);
    __syncthreads();
    if (tid < 128) {
        float t = 0.f;
        #pragma unroll
        for (int j = 0; j < 16; ++j) t += red[j * 128 + tid];
        atomicAdd(sum + tid, t);
    } else {
        int col = tid - 128;
        float t = 0.f;
        #pragma unroll
        for (int j = 0; j < 16; ++j) t += red[2048 + j * 128 + col];
        atomicAdd(sq + col, t);
    }
}

// ---------------------------------------------------------------------------
// Fused BN1-finalize + fold into GEMM2 operands (biasF pre-initialized to b2).
// Block k consumes sum[k]/sq[k] then zeroes them for the next GEMM.
// ---------------------------------------------------------------------------
__global__ __launch_bounds__(128) void k_fold(const float* __restrict__ W2,
                                              float* __restrict__ sum,
                                              float* __restrict__ sq,
                                              const float* __restrict__ g1,
                                              const float* __restrict__ bt1,
                                              float* __restrict__ W2s,
                                              float* __restrict__ biasF) {
    int k = blockIdx.x, j = threadIdx.x;
    float m = sum[k] * (1.f / NN);
    float v = sq[k] * (1.f / NN) - m * m;
    __syncthreads();
    if (j == 0) { sum[k] = 0.f; sq[k] = 0.f; }
    float a = g1[k] * rsqrtf(v + EPS);
    float c = bt1[k] - m * a;
    float w = W2[(long)k * 128 + j];
    W2s[(long)k * 128 + j] = a * w;
    atomicAdd(biasF + j, c * w);
}

// BN2 + outer BN collapse: A = rs2*g2*rso*go, B = bo - m2*A. Zeroes sum/sq.
__global__ void k_fin2(float* __restrict__ sum, float* __restrict__ sq,
                       const float* __restrict__ g2, const float* __restrict__ go,
                       const float* __restrict__ bo, float* __restrict__ affA,
                       float* __restrict__ affB) {
    int f = threadIdx.x;
    float m = sum[f] * (1.f / NN);
    float v = sq[f] * (1.f / NN) - m * m;
    sum[f] = 0.f;
    sq[f] = 0.f;
    float t = g2[f] * rsqrtf(v + EPS);
    float vo = t * t * v;
    float Aa = t * rsqrtf(vo + EPS) * go[f];
    affA[f] = Aa;
    affB[f] = bo[f] - m * Aa;
}

// ---------------------------------------------------------------------------
// Final-layer affine+ReLU, fused with per-graph sum accumulation.
// Thread (rg=tid>>5, f4=tid&31) handles 8 consecutive rows; per-graph runs
// are flushed with 4 atomicAdds into gsum (batch is sorted -> ~1 flush/thread).
// ---------------------------------------------------------------------------
__global__ __launch_bounds__(256) void k_affine_pool(const float4* __restrict__ Y,
                                                     const float* __restrict__ affA,
                                                     const float* __restrict__ affB,
                                                     const int* __restrict__ batch,
                                                     float4* __restrict__ nodeEmb,
                                                     float* __restrict__ gsum) {
    int tid = threadIdx.x;
    int f4 = tid & 31;
    int rg = tid >> 5;
    long base = (long)blockIdx.x * 64 + (long)rg * 8;
    float4 A = *(const float4*)(affA + f4 * 4);
    float4 B = *(const float4*)(affB + f4 * 4);
    float4 run = make_float4(0.f, 0.f, 0.f, 0.f);
    int curg = -1;
    #pragma unroll
    for (int i = 0; i < 8; ++i) {
        long r = base + i;
        if (r >= NN) break;
        int g = batch[r];
        float4 v = Y[r * 32 + f4];
        float4 o;
        o.x = fmaxf(fmaf(v.x, A.x, B.x), 0.f);
        o.y = fmaxf(fmaf(v.y, A.y, B.y), 0.f);
        o.z = fmaxf(fmaf(v.z, A.z, B.z), 0.f);
        o.w = fmaxf(fmaf(v.w, A.w, B.w), 0.f);
        nodeEmb[r * 32 + f4] = o;
        if (g != curg) {
            if (curg >= 0) {
                float* p = gsum + (long)curg * D + f4 * 4;
                atomicAdd(p + 0, run.x); atomicAdd(p + 1, run.y);
                atomicAdd(p + 2, run.z); atomicAdd(p + 3, run.w);
            }
            curg = g;
            run = o;
        } else {
            run.x += o.x; run.y += o.y; run.z += o.z; run.w += o.w;
        }
    }
    if (curg >= 0) {
        float* p = gsum + (long)curg * D + f4 * 4;
        atomicAdd(p + 0, run.x); atomicAdd(p + 1, run.y);
        atomicAdd(p + 2, run.z); atomicAdd(p + 3, run.w);
    }
}

// Finalize: mean from gsum/goff, write ge, fc(128->2) reduce -> out.
__global__ __launch_bounds__(128) void k_fc(const float* __restrict__ gsum,
                                            const int* __restrict__ goff,
                                            const float* __restrict__ fcW,
                                            const float* __restrict__ fcb,
                                            float* __restrict__ ge,
                                            float* __restrict__ out) {
    __shared__ float r0[128], r1[128];
    int g = blockIdx.x, j = threadIdx.x;
    int cnt = goff[g + 1] - goff[g];
    float mean = gsum[(long)g * D + j] / (float)(cnt > 0 ? cnt : 1);
    ge[(long)g * D + j] = mean;
    r0[j] = mean * fcW[j * 2 + 0];
    r1[j] = mean * fcW[j * 2 + 1];
    __syncthreads();
    for (int st = 64; st > 0; st >>= 1) {
        if (j < st) { r0[j] += r0[j + st]; r1[j] += r1[j + st]; }
        __syncthreads();
    }
    if (j == 0) {
        out[g * 2 + 0] = r0[0] + fcb[0];
        out[g * 2 + 1] = r1[0] + fcb[1];
    }
}

// ---------------------------------------------------------------------------
extern "C" void kernel_launch(void* const* d_in, const int* in_sizes, int n_in,
                              void* d_out, int out_size, void* d_ws, size_t ws_size,
                              hipStream_t stream) {
    const float* x   = (const float*)d_in[0];
    const int*   ei  = (const int*)d_in[1];
    const int*   bat = (const int*)d_in[2];
    const float* W1  = (const float*)d_in[3];
    const float* b1  = (const float*)d_in[4];
    const float* g1  = (const float*)d_in[5];
    const float* bt1 = (const float*)d_in[6];
    const float* W2  = (const float*)d_in[7];
    const float* b2  = (const float*)d_in[8];
    const float* g2  = (const float*)d_in[9];
    const float* go  = (const float*)d_in[11];
    const float* bo  = (const float*)d_in[12];
    const float* fcW = (const float*)d_in[13];
    const float* fcb = (const float*)d_in[14];

    const long ND = (long)NN * D;
    float* H = (float*)d_ws;
    float* G = H + ND;
    float* S = G + ND;
    float* sum      = S;                       // 128
    float* sq       = S + 128;                 // 128
    float* gsum     = S + 256;                 // NG*D = 65536
    float* biasFall = S + 65792;               // NL*D = 384
    float* affA     = S + 66176;               // 128
    float* affB     = S + 66304;               // 128
    float* W2s      = S + 66432;               // 16384
    int*   goff     = (int*)(S + 82816);       // NG+1
    int*   off      = (int*)(S + 83840);       // NN+1
    int*   srcs     = off + (NN + 1);          // NE

    float* nodeEmb = (float*)d_out;     // also GEMM1 scratch Y
    float* ge   = nodeEmb + ND;
    float* out2 = ge + (long)NG * D;
    float* Y = nodeEmb;

    // CSR-build temporaries alias into nodeEmb (consumed before first GEMM)
    int* deg  = (int*)nodeEmb;
    int* excl = deg + NN;
    int* cur  = excl + NN;
    int* bsum = cur + NN;

    const int edgeGrid = (NE + 255) / 256;
    const int nodeGrid = (NN + 255) / 256;
    const int gathGrid = (int)(((long)NN * 32 + 255) / 256);
    const int gemmGrid = (NN + BM - 1) / BM;     // 1563
    const int apGrid   = (NN + 63) / 64;         // 1563

    hipMemsetAsync(deg, 0, NN * sizeof(int), stream);
    k_hist<<<edgeGrid, 256, 0, stream>>>(ei, deg);
    k_scan1<<<nodeGrid, 256, 0, stream>>>(deg, excl, bsum);
    k_scan2<<<1, 512, 0, stream>>>(bsum, nodeGrid);
    k_scan3<<<nodeGrid, 256, 0, stream>>>(excl, bsum, off, cur);
    k_fill<<<edgeGrid, 256, 0, stream>>>(ei, cur, srcs);

    // zero sum/sq/gsum in one shot; k_fold/k_fin2 re-zero sum/sq per GEMM
    hipMemsetAsync(sum, 0, (256 + (long)NG * D) * sizeof(float), stream);
    k_goff<<<nodeGrid, 256, 0, stream>>>(bat, goff, b2, biasFall);

    for (int l = 0; l < NL; ++l) {
        if (l == 0)
            k_gather<<<gathGrid, 256, 0, stream>>>((const float4*)x, off, srcs,
                                                   (float4*)G);
        else
            k_gather_aff<<<gathGrid, 256, 0, stream>>>((const float4*)G, off, srcs,
                                                       affA, affB, (float4*)H);
        const float* gin = (l == 0) ? G : H;

        k_gemm<<<gemmGrid, 256, 0, stream>>>(gin, W1 + (long)l * D * D, b1 + l * D,
                                             Y, sum, sq);
        k_fold<<<128, 128, 0, stream>>>(W2 + (long)l * D * D, sum, sq,
                                        g1 + l * D, bt1 + l * D, W2s,
                                        biasFall + (long)l * D);

        k_gemm<<<gemmGrid, 256, 0, stream>>>(Y, W2s, biasFall + (long)l * D,
                                             G, sum, sq);
        k_fin2<<<1, 128, 0, stream>>>(sum, sq, g2 + l * D, go + l * D, bo + l * D,
                                      affA, affB);
    }

    k_affine_pool<<<apGrid, 256, 0, stream>>>((const float4*)G, affA, affB, bat,
                                              (float4*)nodeEmb, gsum);
    k_fc<<<NG, 128, 0, stream>>>(gsum, goff, fcW, fcb, ge, out2);
}